// Round 5
// baseline (344.958 us; speedup 1.0000x reference)
//
#include <hip/hip_runtime.h>
#include <hip/hip_bf16.h>
#include <cstdint>

#define B_ 256
#define P_ 196
#define D_ 512
#define A_ 512

#define OUT_CHAT  0
#define OUT_ALPHA (B_*D_)            // 131072
#define OUT_BETA  (B_*D_ + B_*P_)    // 181248

typedef unsigned short ushort_t;
typedef uint32_t u32;
typedef uint64_t u64;
typedef __attribute__((ext_vector_type(8))) __bf16 bf16x8;
typedef __attribute__((ext_vector_type(4))) float f32x4;

__device__ __forceinline__ ushort_t f2bf(float f) {
    union { float f; u32 i; } v; v.f = f;
    u32 r = (v.i + 0x7fffu + ((v.i >> 16) & 1u)) >> 16;
    return (ushort_t)r;
}
// HW packed f32->bf16 (v_cvt_pk_bf16_f32 on gfx950), x -> low 16 bits
__device__ __forceinline__ u32 cvt2bf(float x, float y) {
    union { __hip_bfloat162 h; u32 u; } v;
    v.h = __float22bfloat162_rn(make_float2(x, y));
    return v.u;
}
// tanh(x) = 1 - 2/(1+e^{2x}); exact at +-inf limits, ~1e-6 abs err
__device__ __forceinline__ float tanh_fast(float x) {
    float e = __expf(2.0f * x);
    return 1.0f - 2.0f / (e + 1.0f);
}

// ---------------- K0: WvT[a][d] = bf16(Wv[d][a]), Wv is f32 ----------------
__global__ __launch_bounds__(256) void k0_transpose(
    const float* __restrict__ Wv, ushort_t* __restrict__ WvT)
{
    __shared__ ushort_t tile[32][33];
    int bx = blockIdx.x, by = blockIdx.y;
    int t = threadIdx.x, r = t >> 5, c = t & 31;
#pragma unroll
    for (int i = 0; i < 4; ++i) {
        int row = r + 8 * i;
        tile[row][c] = f2bf(Wv[(size_t)(by * 32 + row) * A_ + bx * 32 + c]);
    }
    __syncthreads();
#pragma unroll
    for (int i = 0; i < 4; ++i) {
        int row = r + 8 * i;
        WvT[(size_t)(bx * 32 + row) * D_ + by * 32 + c] = tile[c][row];
    }
}

// ------- K1: hidden[b][a] = dh@Wh+bh; s_att[b]; zero z_ws & ct_ws -------
__global__ __launch_bounds__(256) void k1_hidden_satt(
    const float* __restrict__ dh, const float* __restrict__ st,
    const float* __restrict__ Wh, const float* __restrict__ bh,
    const float* __restrict__ Ws, const float* __restrict__ bs,
    const float* __restrict__ Was, const float* __restrict__ bas,
    float* __restrict__ hidden_ws, float* __restrict__ satt_ws,
    float* __restrict__ z_ws, float* __restrict__ ct_ws)
{
    __shared__ float dh_s[D_];
    __shared__ float st_s[D_];
    __shared__ float red[4];
    int b = blockIdx.x, t = threadIdx.x;
    // zero accumulation buffers for this batch row
    if (t < P_) z_ws[(size_t)b * P_ + t] = 0.f;
    ct_ws[(size_t)b * D_ + t]       = 0.f;
    ct_ws[(size_t)b * D_ + t + 256] = 0.f;

    dh_s[t]       = dh[(size_t)b * D_ + t];
    dh_s[t + 256] = dh[(size_t)b * D_ + t + 256];
    st_s[t]       = st[(size_t)b * D_ + t];
    st_s[t + 256] = st[(size_t)b * D_ + t + 256];
    __syncthreads();
    int a0 = 2 * t;
    float hh0 = 0.f, hh1 = 0.f, ss0 = 0.f, ss1 = 0.f;
#pragma unroll 4
    for (int d = 0; d < D_; ++d) {
        float2 wh  = *(const float2*)(Wh + (size_t)d * A_ + a0);
        float2 wsv = *(const float2*)(Ws + (size_t)d * A_ + a0);
        float dv = dh_s[d], sv = st_s[d];
        hh0 = fmaf(dv, wh.x,  hh0);
        hh1 = fmaf(dv, wh.y,  hh1);
        ss0 = fmaf(sv, wsv.x, ss0);
        ss1 = fmaf(sv, wsv.y, ss1);
    }
    float h0 = hh0 + bh[a0], h1 = hh1 + bh[a0 + 1];
    float s0 = ss0 + bs[a0], s1 = ss1 + bs[a0 + 1];
    hidden_ws[(size_t)b * A_ + a0]     = h0;
    hidden_ws[(size_t)b * A_ + a0 + 1] = h1;
    float part = Was[a0]     * tanh_fast(s0 + h0)
               + Was[a0 + 1] * tanh_fast(s1 + h1);
#pragma unroll
    for (int o = 32; o >= 1; o >>= 1) part += __shfl_down(part, o, 64);
    if ((t & 63) == 0) red[t >> 6] = part;
    __syncthreads();
    if (t == 0)
        satt_ws[b] = red[0] + red[1] + red[2] + red[3] + bas[0];
}

// ---- K2: z[b][p] += Wav . tanh(E@Wv + bv + hidden) ----
// GEMM view: M = B*P = 50176 (=392*128), N = 512, K = 512.
// BM=128, BN=128, BK=64; 4 waves, each 64 rows x 64 cols (4x4 MFMA tiles).
// LDS ~39 KB -> 4 blocks/CU = 16 waves/CU.
#define BM 128
#define BN 128
#define BKk 64
#define PADK 72   // LDS row pitch (bf16): 144 B, 16B-aligned, 2-way-max bank alias
__global__ __launch_bounds__(256, 4) void k2_z(
    const float* __restrict__ E, const ushort_t* __restrict__ WvT,
    const float* __restrict__ hidden_ws, const float* __restrict__ bv,
    const float* __restrict__ Wav, float* __restrict__ z_ws)
{
    __shared__ ushort_t As[BM * PADK];   // [m][k]
    __shared__ ushort_t Bs[BN * PADK];   // [n][k]
    __shared__ float hv_s[2][BN];
    __shared__ float wav_s[BN];
    __shared__ float zpart[2][BM];

    int tid = threadIdx.x;
    int m0  = blockIdx.x * BM;
    int n0  = blockIdx.y * BN;
    int b0  = m0 / P_;
    int b1  = (m0 + BM - 1) / P_;   // at most b0+1 since BM < P_

    if (tid < BN) {   // stage hidden+bv (both possible b's) and Wav
        int a = n0 + tid;
        float bva = bv[a];
        hv_s[0][tid] = hidden_ws[(size_t)b0 * A_ + a] + bva;
        hv_s[1][tid] = hidden_ws[(size_t)b1 * A_ + a] + bva;
        wav_s[tid]   = Wav[a];
    }

    int lane = tid & 63, w = tid >> 6;
    int wm = w & 1, wn = w >> 1;
    int col = lane & 15, q = lane >> 4;

    f32x4 acc[4][4];
#pragma unroll
    for (int tm = 0; tm < 4; ++tm)
#pragma unroll
        for (int tn = 0; tn < 4; ++tn)
            acc[tm][tn] = (f32x4){0.f, 0.f, 0.f, 0.f};

    const ushort_t* arow = As + (wm * 64 + col) * PADK + q * 8;
    const ushort_t* brow = Bs + (wn * 64 + col) * PADK + q * 8;

    // staging maps: 2 threads/row, each does half a 64-wide K-chunk (32 elems)
    int r2 = tid >> 1, hf = tid & 1;
    const float4* asrc = (const float4*)(E + (size_t)(m0 + r2) * D_) + hf * 8;
    u32*          adst = (u32*)(As + r2 * PADK + hf * 32);
    const uint4*  bsrc = (const uint4*)(WvT + (size_t)(n0 + r2) * D_);
    uint4*        bdst = (uint4*)(Bs + r2 * PADK + hf * 32);

    for (int kt = 0; kt < D_ / BKk; ++kt) {
        {   // A: 8 float4 -> HW cvt -> 32 bf16
            float4 av[8];
#pragma unroll
            for (int i = 0; i < 8; ++i) av[i] = asrc[kt * 16 + i];
            u32 tmp[16];
#pragma unroll
            for (int i = 0; i < 8; ++i) {
                tmp[2 * i]     = cvt2bf(av[i].x, av[i].y);
                tmp[2 * i + 1] = cvt2bf(av[i].z, av[i].w);
            }
#pragma unroll
            for (int i = 0; i < 4; ++i)
                ((uint4*)adst)[i] = ((const uint4*)tmp)[i];
        }
        {   // B: 4 uint4 (64 B) straight copy
            uint4 bvv[4];
#pragma unroll
            for (int i = 0; i < 4; ++i) bvv[i] = bsrc[kt * 8 + hf * 4 + i];
#pragma unroll
            for (int i = 0; i < 4; ++i) bdst[i] = bvv[i];
        }
        __syncthreads();
#pragma unroll
        for (int ks = 0; ks < 2; ++ks) {
            bf16x8 afr[4];
#pragma unroll
            for (int tm = 0; tm < 4; ++tm)
                afr[tm] = *(const bf16x8*)(arow + tm * 16 * PADK + ks * 32);
#pragma unroll
            for (int tn = 0; tn < 4; ++tn) {
                bf16x8 bfr = *(const bf16x8*)(brow + tn * 16 * PADK + ks * 32);
#pragma unroll
                for (int tm = 0; tm < 4; ++tm)
                    acc[tm][tn] = __builtin_amdgcn_mfma_f32_16x16x32_bf16(
                        afr[tm], bfr, acc[tm][tn], 0, 0, 0);
            }
        }
        __syncthreads();
    }

    // epilogue: z-partial per row over this 128-col chunk
#pragma unroll
    for (int tm = 0; tm < 4; ++tm) {
#pragma unroll
        for (int r = 0; r < 4; ++r) {
            int row = wm * 64 + tm * 16 + q * 4 + r;
            int m   = m0 + row;
            int bsel = (m / P_) - b0;
            float zr = 0.f;
#pragma unroll
            for (int tn = 0; tn < 4; ++tn) {
                int nl = wn * 64 + tn * 16 + col;
                zr += wav_s[nl] * tanh_fast(acc[tm][tn][r] + hv_s[bsel][nl]);
            }
#pragma unroll
            for (int msk = 1; msk < 16; msk <<= 1)
                zr += __shfl_xor(zr, msk, 64);
            if (col == 0) zpart[wn][row] = zr;
        }
    }
    __syncthreads();
    if (tid < BM) {
        int m = m0 + tid;
        int b = m / P_;
        int p = m - b * P_;
        atomicAdd(&z_ws[(size_t)b * P_ + p], zpart[0][tid] + zpart[1][tid]);
    }
}

// ---------------- K3: softmax(z+bav) -> alpha; extended softmax -> beta ----------------
__global__ __launch_bounds__(256) void k3_softmax(
    const float* __restrict__ z_ws, const float* __restrict__ satt_ws,
    const float* __restrict__ bav,
    float* __restrict__ alpha_ws, float* __restrict__ beta_ws,
    float* __restrict__ out)
{
    __shared__ float red[4];
    __shared__ float bm_s, bl_s;
    int b = blockIdx.x, t = threadIdx.x;
    float zv = (t < P_) ? (z_ws[(size_t)b * P_ + t] + bav[0]) : -1e30f;

    float m = zv;
#pragma unroll
    for (int o = 32; o >= 1; o >>= 1) m = fmaxf(m, __shfl_xor(m, o, 64));
    if ((t & 63) == 0) red[t >> 6] = m;
    __syncthreads();
    if (t == 0) bm_s = fmaxf(fmaxf(red[0], red[1]), fmaxf(red[2], red[3]));
    __syncthreads();
    float m1 = bm_s;

    float e = (t < P_) ? __expf(zv - m1) : 0.f;
    float s = e;
#pragma unroll
    for (int o = 32; o >= 1; o >>= 1) s += __shfl_xor(s, o, 64);
    if ((t & 63) == 0) red[t >> 6] = s;
    __syncthreads();
    if (t == 0) bl_s = red[0] + red[1] + red[2] + red[3];
    __syncthreads();
    float l1 = bl_s;

    if (t < P_) {
        float alpha = e / l1;
        alpha_ws[(size_t)b * P_ + t] = alpha;
        out[OUT_ALPHA + (size_t)b * P_ + t] = alpha;
    }
    float sa = satt_ws[b];
    float m2 = fmaxf(m1, sa);
    float l2 = __expf(m1 - m2) * l1 + __expf(sa - m2);
    float beta = __expf(sa - m2) / l2;
    if (t == 0) {
        beta_ws[b] = beta;
        out[OUT_BETA + b] = beta;
    }
}

// ---------------- K4a: ct_ws[b][:] += E[b,pc-chunk]^T alpha ----------------
#define PCH 49
__global__ __launch_bounds__(256) void k4_ct_partial(
    const float* __restrict__ E, const float* __restrict__ alpha_ws,
    float* __restrict__ ct_ws)
{
    __shared__ float al[PCH];
    int b = blockIdx.x, pc = blockIdx.y, t = threadIdx.x;
    int pbase = pc * PCH;
    if (t < PCH) al[t] = alpha_ws[(size_t)b * P_ + pbase + t];
    __syncthreads();
    const float* eb = E + ((size_t)b * P_ + pbase) * D_ + 2 * t;
    float a0 = 0.f, a1 = 0.f;
#pragma unroll 7
    for (int p = 0; p < PCH; ++p) {
        float2 u = *(const float2*)(eb + (size_t)p * D_);
        float ap = al[p];
        a0 = fmaf(ap, u.x, a0);
        a1 = fmaf(ap, u.y, a1);
    }
    atomicAdd(&ct_ws[(size_t)b * D_ + 2 * t],     a0);
    atomicAdd(&ct_ws[(size_t)b * D_ + 2 * t + 1], a1);
}

// ---------------- K4b: c_hat = beta*st + (1-beta)*c_t ----------------
__global__ __launch_bounds__(256) void k4_combine(
    const float* __restrict__ st, const float* __restrict__ ct_ws,
    const float* __restrict__ beta_ws, float* __restrict__ out)
{
    int b = blockIdx.x, t = threadIdx.x;
    float beta = beta_ws[b];
    float2 su = *(const float2*)(st + (size_t)b * D_ + 2 * t);
    float2 cu = *(const float2*)(ct_ws + (size_t)b * D_ + 2 * t);
    float c0 = beta * su.x + (1.f - beta) * cu.x;
    float c1 = beta * su.y + (1.f - beta) * cu.y;
    *(float2*)(out + (size_t)b * D_ + 2 * t) = make_float2(c0, c1);
}

extern "C" void kernel_launch(void* const* d_in, const int* in_sizes, int n_in,
                              void* d_out, int out_size, void* d_ws, size_t ws_size,
                              hipStream_t stream)
{
    (void)in_sizes; (void)n_in; (void)out_size; (void)ws_size;
    const float* E   = (const float*)d_in[0];
    const float* dh  = (const float*)d_in[1];
    const float* st  = (const float*)d_in[2];
    const float* Wv  = (const float*)d_in[3];
    const float* bv  = (const float*)d_in[4];
    const float* Wh  = (const float*)d_in[5];
    const float* bh  = (const float*)d_in[6];
    const float* Ws  = (const float*)d_in[7];
    const float* bs  = (const float*)d_in[8];
    const float* Wav = (const float*)d_in[9];
    const float* bav = (const float*)d_in[10];
    const float* Was = (const float*)d_in[11];
    const float* bas = (const float*)d_in[12];
    float* out = (float*)d_out;

    char* ws = (char*)d_ws;
    ushort_t* WvT      = (ushort_t*)(ws);            // 524288 B (bf16 A x D)
    float*    hidden_w = (float*)(ws + 524288);      // 524288 B
    float*    satt_w   = (float*)(ws + 1048576);     // 1024 B
    float*    z_w      = (float*)(ws + 1049600);     // 200704 B
    float*    alpha_w  = (float*)(ws + 1250304);     // 200704 B
    float*    beta_w   = (float*)(ws + 1451008);     // 1024 B
    float*    ct_w     = (float*)(ws + 1452032);     // 524288 B (total ~1.98 MB)

    k0_transpose<<<dim3(16, 16), 256, 0, stream>>>(Wv, WvT);
    k1_hidden_satt<<<256, 256, 0, stream>>>(dh, st, Wh, bh, Ws, bs, Was, bas,
                                            hidden_w, satt_w, z_w, ct_w);
    k2_z<<<dim3((B_ * P_) / BM, A_ / BN), 256, 0, stream>>>(E, WvT, hidden_w, bv,
                                                            Wav, z_w);
    k3_softmax<<<256, 256, 0, stream>>>(z_w, satt_w, bav, alpha_w, beta_w, out);
    k4_ct_partial<<<dim3(B_, P_ / PCH), 256, 0, stream>>>(E, alpha_w, ct_w);
    k4_combine<<<256, 256, 0, stream>>>(st, ct_w, beta_w, out);
}

// Round 6
// 333.141 us; speedup vs baseline: 1.0355x; 1.0355x over previous
//
#include <hip/hip_runtime.h>
#include <hip/hip_bf16.h>
#include <cstdint>

#define B_ 256
#define P_ 196
#define D_ 512
#define A_ 512

#define OUT_CHAT  0
#define OUT_ALPHA (B_*D_)            // 131072
#define OUT_BETA  (B_*D_ + B_*P_)    // 181248

typedef unsigned short ushort_t;
typedef uint32_t u32;
typedef uint64_t u64;
typedef __attribute__((ext_vector_type(8))) __bf16 bf16x8;
typedef __attribute__((ext_vector_type(4))) float f32x4;

__device__ __forceinline__ ushort_t f2bf(float f) {
    union { float f; u32 i; } v; v.f = f;
    u32 r = (v.i + 0x7fffu + ((v.i >> 16) & 1u)) >> 16;
    return (ushort_t)r;
}
// HW packed f32->bf16 (v_cvt_pk_bf16_f32 on gfx950), x -> low 16 bits
__device__ __forceinline__ u32 cvt2bf(float x, float y) {
    union { __hip_bfloat162 h; u32 u; } v;
    v.h = __float22bfloat162_rn(make_float2(x, y));
    return v.u;
}
// tanh(x) = 1 - 2/(1+e^{2x}); exact at +-inf limits, ~1e-6 abs err
__device__ __forceinline__ float tanh_fast(float x) {
    float e = __expf(2.0f * x);
    return 1.0f - 2.0f / (e + 1.0f);
}

// ---------------- K0: WvT[a][d] = bf16(Wv[d][a]), Wv is f32 ----------------
__global__ __launch_bounds__(256) void k0_transpose(
    const float* __restrict__ Wv, ushort_t* __restrict__ WvT)
{
    __shared__ ushort_t tile[32][33];
    int bx = blockIdx.x, by = blockIdx.y;
    int t = threadIdx.x, r = t >> 5, c = t & 31;
#pragma unroll
    for (int i = 0; i < 4; ++i) {
        int row = r + 8 * i;
        tile[row][c] = f2bf(Wv[(size_t)(by * 32 + row) * A_ + bx * 32 + c]);
    }
    __syncthreads();
#pragma unroll
    for (int i = 0; i < 4; ++i) {
        int row = r + 8 * i;
        WvT[(size_t)(bx * 32 + row) * D_ + by * 32 + c] = tile[c][row];
    }
}

// ---------------- kE: Ebf = bf16(E), 2 float4 per thread ----------------
__global__ __launch_bounds__(256) void kE_cvt(
    const float* __restrict__ E, ushort_t* __restrict__ Ebf)
{
    size_t i0 = (size_t)blockIdx.x * 512 + threadIdx.x;   // float4 index
    const float4* src = (const float4*)E;
    u64* dst = (u64*)Ebf;
    float4 v0 = src[i0];
    float4 v1 = src[i0 + 256];
    u64 p0 = (u64)cvt2bf(v0.x, v0.y) | ((u64)cvt2bf(v0.z, v0.w) << 32);
    u64 p1 = (u64)cvt2bf(v1.x, v1.y) | ((u64)cvt2bf(v1.z, v1.w) << 32);
    dst[i0]       = p0;
    dst[i0 + 256] = p1;
}

// ------- K1: hidden[b][a] = dh@Wh+bh; s_att[b]; zero z_ws & ct_ws -------
// 4 batches per block: weight traffic 512 MB -> 128 MB, 16 fma per 16 B loaded.
#define KNB 4
__global__ __launch_bounds__(256) void k1_hidden_satt(
    const float* __restrict__ dh, const float* __restrict__ st,
    const float* __restrict__ Wh, const float* __restrict__ bh,
    const float* __restrict__ Ws, const float* __restrict__ bs,
    const float* __restrict__ Was, const float* __restrict__ bas,
    float* __restrict__ hidden_ws, float* __restrict__ satt_ws,
    float* __restrict__ z_ws, float* __restrict__ ct_ws)
{
    __shared__ float dh_s[KNB][D_];
    __shared__ float st_s[KNB][D_];
    __shared__ float red[KNB][4];
    int b0 = blockIdx.x * KNB, t = threadIdx.x;

#pragma unroll
    for (int j = 0; j < KNB; ++j) {
        int b = b0 + j;
        if (t < P_) z_ws[(size_t)b * P_ + t] = 0.f;
        ct_ws[(size_t)b * D_ + t]       = 0.f;
        ct_ws[(size_t)b * D_ + t + 256] = 0.f;
        dh_s[j][t]       = dh[(size_t)b * D_ + t];
        dh_s[j][t + 256] = dh[(size_t)b * D_ + t + 256];
        st_s[j][t]       = st[(size_t)b * D_ + t];
        st_s[j][t + 256] = st[(size_t)b * D_ + t + 256];
    }
    __syncthreads();

    int a0 = 2 * t;
    float hh[KNB][2], ss[KNB][2];
#pragma unroll
    for (int j = 0; j < KNB; ++j) {
        hh[j][0] = hh[j][1] = 0.f;
        ss[j][0] = ss[j][1] = 0.f;
    }
#pragma unroll 4
    for (int d = 0; d < D_; ++d) {
        float2 wh  = *(const float2*)(Wh + (size_t)d * A_ + a0);
        float2 wsv = *(const float2*)(Ws + (size_t)d * A_ + a0);
#pragma unroll
        for (int j = 0; j < KNB; ++j) {
            float dv = dh_s[j][d], sv = st_s[j][d];
            hh[j][0] = fmaf(dv, wh.x,  hh[j][0]);
            hh[j][1] = fmaf(dv, wh.y,  hh[j][1]);
            ss[j][0] = fmaf(sv, wsv.x, ss[j][0]);
            ss[j][1] = fmaf(sv, wsv.y, ss[j][1]);
        }
    }
    float bh0 = bh[a0], bh1 = bh[a0 + 1];
    float bs0 = bs[a0], bs1 = bs[a0 + 1];
    float wa0 = Was[a0], wa1 = Was[a0 + 1];
#pragma unroll
    for (int j = 0; j < KNB; ++j) {
        int b = b0 + j;
        float h0 = hh[j][0] + bh0, h1 = hh[j][1] + bh1;
        float s0 = ss[j][0] + bs0, s1 = ss[j][1] + bs1;
        hidden_ws[(size_t)b * A_ + a0]     = h0;
        hidden_ws[(size_t)b * A_ + a0 + 1] = h1;
        float part = wa0 * tanh_fast(s0 + h0) + wa1 * tanh_fast(s1 + h1);
#pragma unroll
        for (int o = 32; o >= 1; o >>= 1) part += __shfl_down(part, o, 64);
        if ((t & 63) == 0) red[j][t >> 6] = part;
    }
    __syncthreads();
    if (t < KNB)
        satt_ws[b0 + t] = red[t][0] + red[t][1] + red[t][2] + red[t][3] + bas[0];
}

// ---- K2 (bf16-E): z += Wav . tanh(Ebf@Wv + bv + hidden) ----
// BM=128, BN=256, BK=64; 4 waves, each 64 rows x 128 cols (4x8), 64 MFMA/barrier.
#define BM 128
#define BN 256
#define BKk 64
#define PADK 72   // LDS pitch 144 B: 16B-aligned, 2-way-max bank alias on frag reads
__global__ __launch_bounds__(256, 2) void k2_z_bf(
    const ushort_t* __restrict__ Ebf, const ushort_t* __restrict__ WvT,
    const float* __restrict__ hidden_ws, const float* __restrict__ bv,
    const float* __restrict__ Wav, float* __restrict__ z_ws)
{
    __shared__ ushort_t As[BM * PADK];
    __shared__ ushort_t Bs[BN * PADK];
    __shared__ float hv_s[2][BN];
    __shared__ float wav_s[BN];
    __shared__ float zpart[2][BM];

    int tid = threadIdx.x;
    int m0  = blockIdx.x * BM;
    int n0  = blockIdx.y * BN;
    int b0  = m0 / P_;
    int b1  = (m0 + BM - 1) / P_;

    {
        int a = n0 + tid;
        float bva = bv[a];
        hv_s[0][tid] = hidden_ws[(size_t)b0 * A_ + a] + bva;
        hv_s[1][tid] = hidden_ws[(size_t)b1 * A_ + a] + bva;
        wav_s[tid]   = Wav[a];
    }

    int lane = tid & 63, w = tid >> 6;
    int wm = w & 1, wn = w >> 1;
    int col = lane & 15, q = lane >> 4;

    f32x4 acc[4][8];
#pragma unroll
    for (int tm = 0; tm < 4; ++tm)
#pragma unroll
        for (int tn = 0; tn < 8; ++tn)
            acc[tm][tn] = (f32x4){0.f, 0.f, 0.f, 0.f};

    const ushort_t* arow = As + (wm * 64 + col) * PADK + q * 8;
    const ushort_t* brow = Bs + (wn * 128 + col) * PADK + q * 8;

    // staging map: 8 threads/row, 16 B each -> contiguous 128 B per row
    int sr = tid >> 3, sc = tid & 7;

    for (int kt = 0; kt < D_ / BKk; ++kt) {
        {   // A: 128 rows x 128 B, 4 passes of 32 rows
#pragma unroll
            for (int i = 0; i < 4; ++i) {
                int row = sr + i * 32;
                *(uint4*)(As + row * PADK + sc * 8) =
                    *(const uint4*)(Ebf + (size_t)(m0 + row) * D_ + kt * BKk + sc * 8);
            }
        }
        {   // B: 256 rows x 128 B, 8 passes of 32 rows
#pragma unroll
            for (int i = 0; i < 8; ++i) {
                int row = sr + i * 32;
                *(uint4*)(Bs + row * PADK + sc * 8) =
                    *(const uint4*)(WvT + (size_t)(n0 + row) * D_ + kt * BKk + sc * 8);
            }
        }
        __syncthreads();
#pragma unroll
        for (int ks = 0; ks < 2; ++ks) {
            bf16x8 afr[4], bfr[8];
#pragma unroll
            for (int tm = 0; tm < 4; ++tm)
                afr[tm] = *(const bf16x8*)(arow + tm * 16 * PADK + ks * 32);
#pragma unroll
            for (int tn = 0; tn < 8; ++tn)
                bfr[tn] = *(const bf16x8*)(brow + tn * 16 * PADK + ks * 32);
#pragma unroll
            for (int tm = 0; tm < 4; ++tm)
#pragma unroll
                for (int tn = 0; tn < 8; ++tn)
                    acc[tm][tn] = __builtin_amdgcn_mfma_f32_16x16x32_bf16(
                        afr[tm], bfr[tn], acc[tm][tn], 0, 0, 0);
        }
        __syncthreads();
    }

#pragma unroll
    for (int tm = 0; tm < 4; ++tm) {
#pragma unroll
        for (int r = 0; r < 4; ++r) {
            int row = wm * 64 + tm * 16 + q * 4 + r;
            int m   = m0 + row;
            int bsel = (m / P_) - b0;
            float zr = 0.f;
#pragma unroll
            for (int tn = 0; tn < 8; ++tn) {
                int nl = wn * 128 + tn * 16 + col;
                zr += wav_s[nl] * tanh_fast(acc[tm][tn][r] + hv_s[bsel][nl]);
            }
#pragma unroll
            for (int msk = 1; msk < 16; msk <<= 1)
                zr += __shfl_xor(zr, msk, 64);
            if (col == 0) zpart[wn][row] = zr;
        }
    }
    __syncthreads();
    if (tid < BM) {
        int m = m0 + tid;
        int b = m / P_;
        int p = m - b * P_;
        atomicAdd(&z_ws[(size_t)b * P_ + p], zpart[0][tid] + zpart[1][tid]);
    }
}

// ---- K2 fallback (f32 E, round-4 version) if ws too small for Ebf ----
__global__ __launch_bounds__(256, 2) void k2_z_f32(
    const float* __restrict__ E, const ushort_t* __restrict__ WvT,
    const float* __restrict__ hidden_ws, const float* __restrict__ bv,
    const float* __restrict__ Wav, float* __restrict__ z_ws)
{
    __shared__ ushort_t As[BM * PADK];
    __shared__ ushort_t Bs[BN * PADK];
    __shared__ float hv_s[2][BN];
    __shared__ float wav_s[BN];
    __shared__ float zpart[2][BM];

    int tid = threadIdx.x;
    int m0  = blockIdx.x * BM;
    int n0  = blockIdx.y * BN;
    int b0  = m0 / P_;
    int b1  = (m0 + BM - 1) / P_;

    {
        int a = n0 + tid;
        float bva = bv[a];
        hv_s[0][tid] = hidden_ws[(size_t)b0 * A_ + a] + bva;
        hv_s[1][tid] = hidden_ws[(size_t)b1 * A_ + a] + bva;
        wav_s[tid]   = Wav[a];
    }

    int lane = tid & 63, w = tid >> 6;
    int wm = w & 1, wn = w >> 1;
    int col = lane & 15, q = lane >> 4;

    f32x4 acc[4][8];
#pragma unroll
    for (int tm = 0; tm < 4; ++tm)
#pragma unroll
        for (int tn = 0; tn < 8; ++tn)
            acc[tm][tn] = (f32x4){0.f, 0.f, 0.f, 0.f};

    const ushort_t* arow = As + (wm * 64 + col) * PADK + q * 8;
    const ushort_t* brow = Bs + (wn * 128 + col) * PADK + q * 8;

    for (int kt = 0; kt < D_ / BKk; ++kt) {
        {   // A: 128 rows x 64 f32 -> bf16; 2 threads/row
            int r = tid >> 1, half = tid & 1;
            const float4* src = (const float4*)(E + (size_t)(m0 + r) * D_ + kt * BKk + half * 32);
            u64* dst = (u64*)(As + r * PADK + half * 32);
#pragma unroll
            for (int i = 0; i < 8; ++i) {
                float4 v = src[i];
                dst[i] = (u64)cvt2bf(v.x, v.y) | ((u64)cvt2bf(v.z, v.w) << 32);
            }
        }
        {   // B: 256 rows x 64 bf16; 1 thread/row
            const uint4* src = (const uint4*)(WvT + (size_t)(n0 + tid) * D_ + kt * BKk);
            uint4* dst = (uint4*)(Bs + tid * PADK);
#pragma unroll
            for (int i = 0; i < 8; ++i) dst[i] = src[i];
        }
        __syncthreads();
#pragma unroll
        for (int ks = 0; ks < 2; ++ks) {
            bf16x8 afr[4], bfr[8];
#pragma unroll
            for (int tm = 0; tm < 4; ++tm)
                afr[tm] = *(const bf16x8*)(arow + tm * 16 * PADK + ks * 32);
#pragma unroll
            for (int tn = 0; tn < 8; ++tn)
                bfr[tn] = *(const bf16x8*)(brow + tn * 16 * PADK + ks * 32);
#pragma unroll
            for (int tm = 0; tm < 4; ++tm)
#pragma unroll
                for (int tn = 0; tn < 8; ++tn)
                    acc[tm][tn] = __builtin_amdgcn_mfma_f32_16x16x32_bf16(
                        afr[tm], bfr[tn], acc[tm][tn], 0, 0, 0);
        }
        __syncthreads();
    }

#pragma unroll
    for (int tm = 0; tm < 4; ++tm) {
#pragma unroll
        for (int r = 0; r < 4; ++r) {
            int row = wm * 64 + tm * 16 + q * 4 + r;
            int m   = m0 + row;
            int bsel = (m / P_) - b0;
            float zr = 0.f;
#pragma unroll
            for (int tn = 0; tn < 8; ++tn) {
                int nl = wn * 128 + tn * 16 + col;
                zr += wav_s[nl] * tanh_fast(acc[tm][tn][r] + hv_s[bsel][nl]);
            }
#pragma unroll
            for (int msk = 1; msk < 16; msk <<= 1)
                zr += __shfl_xor(zr, msk, 64);
            if (col == 0) zpart[wn][row] = zr;
        }
    }
    __syncthreads();
    if (tid < BM) {
        int m = m0 + tid;
        int b = m / P_;
        int p = m - b * P_;
        atomicAdd(&z_ws[(size_t)b * P_ + p], zpart[0][tid] + zpart[1][tid]);
    }
}

// ---------------- K3: softmax(z+bav) -> alpha; extended softmax -> beta ----------------
__global__ __launch_bounds__(256) void k3_softmax(
    const float* __restrict__ z_ws, const float* __restrict__ satt_ws,
    const float* __restrict__ bav,
    float* __restrict__ alpha_ws, float* __restrict__ beta_ws,
    float* __restrict__ out)
{
    __shared__ float red[4];
    __shared__ float bm_s, bl_s;
    int b = blockIdx.x, t = threadIdx.x;
    float zv = (t < P_) ? (z_ws[(size_t)b * P_ + t] + bav[0]) : -1e30f;

    float m = zv;
#pragma unroll
    for (int o = 32; o >= 1; o >>= 1) m = fmaxf(m, __shfl_xor(m, o, 64));
    if ((t & 63) == 0) red[t >> 6] = m;
    __syncthreads();
    if (t == 0) bm_s = fmaxf(fmaxf(red[0], red[1]), fmaxf(red[2], red[3]));
    __syncthreads();
    float m1 = bm_s;

    float e = (t < P_) ? __expf(zv - m1) : 0.f;
    float s = e;
#pragma unroll
    for (int o = 32; o >= 1; o >>= 1) s += __shfl_xor(s, o, 64);
    if ((t & 63) == 0) red[t >> 6] = s;
    __syncthreads();
    if (t == 0) bl_s = red[0] + red[1] + red[2] + red[3];
    __syncthreads();
    float l1 = bl_s;

    if (t < P_) {
        float alpha = e / l1;
        alpha_ws[(size_t)b * P_ + t] = alpha;
        out[OUT_ALPHA + (size_t)b * P_ + t] = alpha;
    }
    float sa = satt_ws[b];
    float m2 = fmaxf(m1, sa);
    float l2 = __expf(m1 - m2) * l1 + __expf(sa - m2);
    float beta = __expf(sa - m2) / l2;
    if (t == 0) {
        beta_ws[b] = beta;
        out[OUT_BETA + b] = beta;
    }
}

// ---------------- K4a: ct_ws[b][:] += E[b,pc-chunk]^T alpha ----------------
#define PCH 49
__global__ __launch_bounds__(256) void k4_ct_partial(
    const float* __restrict__ E, const float* __restrict__ alpha_ws,
    float* __restrict__ ct_ws)
{
    __shared__ float al[PCH];
    int b = blockIdx.x, pc = blockIdx.y, t = threadIdx.x;
    int pbase = pc * PCH;
    if (t < PCH) al[t] = alpha_ws[(size_t)b * P_ + pbase + t];
    __syncthreads();
    const float* eb = E + ((size_t)b * P_ + pbase) * D_ + 2 * t;
    float a0 = 0.f, a1 = 0.f;
#pragma unroll 7
    for (int p = 0; p < PCH; ++p) {
        float2 u = *(const float2*)(eb + (size_t)p * D_);
        float ap = al[p];
        a0 = fmaf(ap, u.x, a0);
        a1 = fmaf(ap, u.y, a1);
    }
    atomicAdd(&ct_ws[(size_t)b * D_ + 2 * t],     a0);
    atomicAdd(&ct_ws[(size_t)b * D_ + 2 * t + 1], a1);
}

// ---------------- K4b: c_hat = beta*st + (1-beta)*c_t ----------------
__global__ __launch_bounds__(256) void k4_combine(
    const float* __restrict__ st, const float* __restrict__ ct_ws,
    const float* __restrict__ beta_ws, float* __restrict__ out)
{
    int b = blockIdx.x, t = threadIdx.x;
    float beta = beta_ws[b];
    float2 su = *(const float2*)(st + (size_t)b * D_ + 2 * t);
    float2 cu = *(const float2*)(ct_ws + (size_t)b * D_ + 2 * t);
    float c0 = beta * su.x + (1.f - beta) * cu.x;
    float c1 = beta * su.y + (1.f - beta) * cu.y;
    *(float2*)(out + (size_t)b * D_ + 2 * t) = make_float2(c0, c1);
}

extern "C" void kernel_launch(void* const* d_in, const int* in_sizes, int n_in,
                              void* d_out, int out_size, void* d_ws, size_t ws_size,
                              hipStream_t stream)
{
    (void)in_sizes; (void)n_in; (void)out_size;
    const float* E   = (const float*)d_in[0];
    const float* dh  = (const float*)d_in[1];
    const float* st  = (const float*)d_in[2];
    const float* Wv  = (const float*)d_in[3];
    const float* bv  = (const float*)d_in[4];
    const float* Wh  = (const float*)d_in[5];
    const float* bh  = (const float*)d_in[6];
    const float* Ws  = (const float*)d_in[7];
    const float* bs  = (const float*)d_in[8];
    const float* Wav = (const float*)d_in[9];
    const float* bav = (const float*)d_in[10];
    const float* Was = (const float*)d_in[11];
    const float* bas = (const float*)d_in[12];
    float* out = (float*)d_out;

    char* ws = (char*)d_ws;
    ushort_t* WvT      = (ushort_t*)(ws);            // 524288 B (bf16 A x D)
    float*    hidden_w = (float*)(ws + 524288);      // 524288 B
    float*    satt_w   = (float*)(ws + 1048576);     // 1024 B
    float*    z_w      = (float*)(ws + 1049600);     // 200704 B
    float*    alpha_w  = (float*)(ws + 1250304);     // 200704 B
    float*    beta_w   = (float*)(ws + 1451008);     // 1024 B
    float*    ct_w     = (float*)(ws + 1452032);     // 524288 B
    ushort_t* Ebf      = (ushort_t*)(ws + 1976320);  // 51380224 B (bf16 B*P x D)
    const size_t WS_NEED = 1976320 + (size_t)B_ * P_ * D_ * 2;

    k0_transpose<<<dim3(16, 16), 256, 0, stream>>>(Wv, WvT);
    k1_hidden_satt<<<B_ / KNB, 256, 0, stream>>>(dh, st, Wh, bh, Ws, bs, Was, bas,
                                                 hidden_w, satt_w, z_w, ct_w);
    if (ws_size >= WS_NEED) {
        kE_cvt<<<(B_ * P_ * D_) / 4 / 512, 256, 0, stream>>>(E, Ebf);
        k2_z_bf<<<dim3((B_ * P_) / BM, A_ / BN), 256, 0, stream>>>(
            Ebf, WvT, hidden_w, bv, Wav, z_w);
    } else {
        k2_z_f32<<<dim3((B_ * P_) / BM, A_ / BN), 256, 0, stream>>>(
            E, WvT, hidden_w, bv, Wav, z_w);
    }
    k3_softmax<<<256, 256, 0, stream>>>(z_w, satt_w, bav, alpha_w, beta_w, out);
    k4_ct_partial<<<dim3(B_, P_ / PCH), 256, 0, stream>>>(E, alpha_w, ct_w);
    k4_combine<<<256, 256, 0, stream>>>(st, ct_w, beta_w, out);
}

// Round 7
// 274.093 us; speedup vs baseline: 1.2585x; 1.2154x over previous
//
#include <hip/hip_runtime.h>
#include <hip/hip_bf16.h>
#include <cstdint>

#define B_ 256
#define P_ 196
#define D_ 512
#define A_ 512

#define OUT_CHAT  0
#define OUT_ALPHA (B_*D_)            // 131072
#define OUT_BETA  (B_*D_ + B_*P_)    // 181248

typedef unsigned short ushort_t;
typedef uint32_t u32;
typedef uint64_t u64;
typedef __attribute__((ext_vector_type(8))) __bf16 bf16x8;
typedef __attribute__((ext_vector_type(4))) float f32x4;

__device__ __forceinline__ ushort_t f2bf(float f) {
    union { float f; u32 i; } v; v.f = f;
    u32 r = (v.i + 0x7fffu + ((v.i >> 16) & 1u)) >> 16;
    return (ushort_t)r;
}
// HW packed f32->bf16 (v_cvt_pk_bf16_f32 on gfx950), x -> low 16 bits
__device__ __forceinline__ u32 cvt2bf(float x, float y) {
    union { __hip_bfloat162 h; u32 u; } v;
    v.h = __float22bfloat162_rn(make_float2(x, y));
    return v.u;
}
// tanh(x) = 1 - 2/(1+e^{2x}); exact at +-inf limits, ~1e-6 abs err
__device__ __forceinline__ float tanh_fast(float x) {
    float e = __expf(2.0f * x);
    return 1.0f - 2.0f / (e + 1.0f);
}

// ------- K0: WT[a][d] = bf16(W[d][a]) for W in {Wv, Wh, Ws} -------
__global__ __launch_bounds__(256) void k0_transpose(
    const float* __restrict__ W, ushort_t* __restrict__ WT)
{
    __shared__ ushort_t tile[32][33];
    int bx = blockIdx.x, by = blockIdx.y;
    int t = threadIdx.x, r = t >> 5, c = t & 31;
#pragma unroll
    for (int i = 0; i < 4; ++i) {
        int row = r + 8 * i;
        tile[row][c] = f2bf(W[(size_t)(by * 32 + row) * A_ + bx * 32 + c]);
    }
    __syncthreads();
#pragma unroll
    for (int i = 0; i < 4; ++i) {
        int row = r + 8 * i;
        WT[(size_t)(bx * 32 + row) * D_ + by * 32 + c] = tile[c][row];
    }
}

// ---- kcvt_small: dh,st -> bf16; zero z_ws, ct_ws. grid 128 x 256 ----
__global__ __launch_bounds__(256) void kcvt_small(
    const float* __restrict__ dh, const float* __restrict__ st,
    ushort_t* __restrict__ dhbf, ushort_t* __restrict__ stbf,
    float* __restrict__ z_ws, float* __restrict__ ct_ws)
{
    int gid = blockIdx.x * 256 + threadIdx.x;       // 0..32767
    const float4* dsrc = (const float4*)dh;
    const float4* ssrc = (const float4*)st;
    float4 dv = dsrc[gid], sv = ssrc[gid];
    ((u64*)dhbf)[gid] = (u64)cvt2bf(dv.x, dv.y) | ((u64)cvt2bf(dv.z, dv.w) << 32);
    ((u64*)stbf)[gid] = (u64)cvt2bf(sv.x, sv.y) | ((u64)cvt2bf(sv.z, sv.w) << 32);
    ((float4*)ct_ws)[gid] = (float4){0.f, 0.f, 0.f, 0.f};
    z_ws[gid < B_ * P_ ? gid : 0] = 0.f;
    if (gid < B_ * P_ - 32768) z_ws[gid + 32768] = 0.f;
}

// ---------------- kE: Ebf = bf16(E), 2 float4 per thread ----------------
__global__ __launch_bounds__(256) void kE_cvt(
    const float* __restrict__ E, ushort_t* __restrict__ Ebf)
{
    size_t i0 = (size_t)blockIdx.x * 512 + threadIdx.x;   // float4 index
    const float4* src = (const float4*)E;
    u64* dst = (u64*)Ebf;
    float4 v0 = src[i0];
    float4 v1 = src[i0 + 256];
    u64 p0 = (u64)cvt2bf(v0.x, v0.y) | ((u64)cvt2bf(v0.z, v0.w) << 32);
    u64 p1 = (u64)cvt2bf(v1.x, v1.y) | ((u64)cvt2bf(v1.z, v1.w) << 32);
    dst[i0]       = p0;
    dst[i0 + 256] = p1;
}

#define PADK 72   // LDS pitch 144 B: 16B-aligned, 2-way-max bank alias

// ---- k1_mfma: hidden = dh@Wh+bh (z=0) and s = st@Ws+bs (z=1) ----
// M=256, N=512, K=512. BM=128, BN=128; grid (4 n-tiles, 2 m-tiles, 2 mats).
__global__ __launch_bounds__(256) void k1_mfma(
    const ushort_t* __restrict__ dhbf, const ushort_t* __restrict__ stbf,
    const ushort_t* __restrict__ WhT,  const ushort_t* __restrict__ WsT,
    const float* __restrict__ bh, const float* __restrict__ bs,
    float* __restrict__ hidden_ws, float* __restrict__ s_ws)
{
    __shared__ ushort_t As[128 * PADK];
    __shared__ ushort_t Bs[128 * PADK];

    int mat = blockIdx.z;
    const ushort_t* Abf = mat ? stbf : dhbf;
    const ushort_t* WT  = mat ? WsT  : WhT;
    const float*    bia = mat ? bs   : bh;
    float*          outp = mat ? s_ws : hidden_ws;

    int tid = threadIdx.x;
    int m0 = blockIdx.y * 128;
    int n0 = blockIdx.x * 128;

    int lane = tid & 63, w = tid >> 6;
    int wm = w & 1, wn = w >> 1;
    int col = lane & 15, q = lane >> 4;

    f32x4 acc[4][4];
#pragma unroll
    for (int tm = 0; tm < 4; ++tm)
#pragma unroll
        for (int tn = 0; tn < 4; ++tn)
            acc[tm][tn] = (f32x4){0.f, 0.f, 0.f, 0.f};

    const ushort_t* arow = As + (wm * 64 + col) * PADK + q * 8;
    const ushort_t* brow = Bs + (wn * 64 + col) * PADK + q * 8;

    int sr = tid >> 3, sc = tid & 7;
    for (int kt = 0; kt < D_ / 64; ++kt) {
#pragma unroll
        for (int i = 0; i < 4; ++i) {
            int row = sr + i * 32;
            *(uint4*)(As + row * PADK + sc * 8) =
                *(const uint4*)(Abf + (size_t)(m0 + row) * D_ + kt * 64 + sc * 8);
            *(uint4*)(Bs + row * PADK + sc * 8) =
                *(const uint4*)(WT + (size_t)(n0 + row) * D_ + kt * 64 + sc * 8);
        }
        __syncthreads();
#pragma unroll
        for (int ks = 0; ks < 2; ++ks) {
            bf16x8 afr[4];
#pragma unroll
            for (int tm = 0; tm < 4; ++tm)
                afr[tm] = *(const bf16x8*)(arow + tm * 16 * PADK + ks * 32);
#pragma unroll
            for (int tn = 0; tn < 4; ++tn) {
                bf16x8 bfr = *(const bf16x8*)(brow + tn * 16 * PADK + ks * 32);
#pragma unroll
                for (int tm = 0; tm < 4; ++tm)
                    acc[tm][tn] = __builtin_amdgcn_mfma_f32_16x16x32_bf16(
                        afr[tm], bfr, acc[tm][tn], 0, 0, 0);
            }
        }
        __syncthreads();
    }

#pragma unroll
    for (int tm = 0; tm < 4; ++tm)
#pragma unroll
        for (int r = 0; r < 4; ++r) {
            int b = m0 + wm * 64 + tm * 16 + q * 4 + r;
#pragma unroll
            for (int tn = 0; tn < 4; ++tn) {
                int n = n0 + wn * 64 + tn * 16 + col;
                outp[(size_t)b * A_ + n] = acc[tm][tn][r] + bia[n];
            }
        }
}

// ---- K2 (bf16-E): z += Wav . tanh(Ebf@Wv + bv + hidden) ----
// BM=128, BN=256, BK=64; 4 waves, each 64 rows x 128 cols (4x8), 64 MFMA/barrier.
#define BM 128
#define BN 256
#define BKk 64
__global__ __launch_bounds__(256, 2) void k2_z_bf(
    const ushort_t* __restrict__ Ebf, const ushort_t* __restrict__ WvT,
    const float* __restrict__ hidden_ws, const float* __restrict__ bv,
    const float* __restrict__ Wav, float* __restrict__ z_ws)
{
    __shared__ ushort_t As[BM * PADK];
    __shared__ ushort_t Bs[BN * PADK];
    __shared__ float hv_s[2][BN];
    __shared__ float wav_s[BN];
    __shared__ float zpart[2][BM];

    int tid = threadIdx.x;
    int m0  = blockIdx.x * BM;
    int n0  = blockIdx.y * BN;
    int b0  = m0 / P_;
    int b1  = (m0 + BM - 1) / P_;

    {
        int a = n0 + tid;
        float bva = bv[a];
        hv_s[0][tid] = hidden_ws[(size_t)b0 * A_ + a] + bva;
        hv_s[1][tid] = hidden_ws[(size_t)b1 * A_ + a] + bva;
        wav_s[tid]   = Wav[a];
    }

    int lane = tid & 63, w = tid >> 6;
    int wm = w & 1, wn = w >> 1;
    int col = lane & 15, q = lane >> 4;

    f32x4 acc[4][8];
#pragma unroll
    for (int tm = 0; tm < 4; ++tm)
#pragma unroll
        for (int tn = 0; tn < 8; ++tn)
            acc[tm][tn] = (f32x4){0.f, 0.f, 0.f, 0.f};

    const ushort_t* arow = As + (wm * 64 + col) * PADK + q * 8;
    const ushort_t* brow = Bs + (wn * 128 + col) * PADK + q * 8;

    int sr = tid >> 3, sc = tid & 7;

    for (int kt = 0; kt < D_ / BKk; ++kt) {
#pragma unroll
        for (int i = 0; i < 4; ++i) {
            int row = sr + i * 32;
            *(uint4*)(As + row * PADK + sc * 8) =
                *(const uint4*)(Ebf + (size_t)(m0 + row) * D_ + kt * BKk + sc * 8);
        }
#pragma unroll
        for (int i = 0; i < 8; ++i) {
            int row = sr + i * 32;
            *(uint4*)(Bs + row * PADK + sc * 8) =
                *(const uint4*)(WvT + (size_t)(n0 + row) * D_ + kt * BKk + sc * 8);
        }
        __syncthreads();
#pragma unroll
        for (int ks = 0; ks < 2; ++ks) {
            bf16x8 afr[4], bfr[8];
#pragma unroll
            for (int tm = 0; tm < 4; ++tm)
                afr[tm] = *(const bf16x8*)(arow + tm * 16 * PADK + ks * 32);
#pragma unroll
            for (int tn = 0; tn < 8; ++tn)
                bfr[tn] = *(const bf16x8*)(brow + tn * 16 * PADK + ks * 32);
#pragma unroll
            for (int tm = 0; tm < 4; ++tm)
#pragma unroll
                for (int tn = 0; tn < 8; ++tn)
                    acc[tm][tn] = __builtin_amdgcn_mfma_f32_16x16x32_bf16(
                        afr[tm], bfr[tn], acc[tm][tn], 0, 0, 0);
        }
        __syncthreads();
    }

#pragma unroll
    for (int tm = 0; tm < 4; ++tm) {
#pragma unroll
        for (int r = 0; r < 4; ++r) {
            int row = wm * 64 + tm * 16 + q * 4 + r;
            int m   = m0 + row;
            int bsel = (m / P_) - b0;
            float zr = 0.f;
#pragma unroll
            for (int tn = 0; tn < 8; ++tn) {
                int nl = wn * 128 + tn * 16 + col;
                zr += wav_s[nl] * tanh_fast(acc[tm][tn][r] + hv_s[bsel][nl]);
            }
#pragma unroll
            for (int msk = 1; msk < 16; msk <<= 1)
                zr += __shfl_xor(zr, msk, 64);
            if (col == 0) zpart[wn][row] = zr;
        }
    }
    __syncthreads();
    if (tid < BM) {
        int m = m0 + tid;
        int b = m / P_;
        int p = m - b * P_;
        atomicAdd(&z_ws[(size_t)b * P_ + p], zpart[0][tid] + zpart[1][tid]);
    }
}

// ---- K3: s_att from (s,hidden); softmax(z+bav) -> alpha; extended -> beta ----
__global__ __launch_bounds__(256) void k3_softmax(
    const float* __restrict__ z_ws, const float* __restrict__ hidden_ws,
    const float* __restrict__ s_ws, const float* __restrict__ Was,
    const float* __restrict__ bas, const float* __restrict__ bav,
    float* __restrict__ alpha_ws, float* __restrict__ beta_ws,
    float* __restrict__ out)
{
    __shared__ float red[4];
    __shared__ float bm_s, bl_s, sa_s;
    int b = blockIdx.x, t = threadIdx.x;

    // s_att = Was . tanh(s + hidden) + bas
    {
        int a0 = t, a1 = t + 256;
        float part = Was[a0] * tanh_fast(s_ws[(size_t)b * A_ + a0] + hidden_ws[(size_t)b * A_ + a0])
                   + Was[a1] * tanh_fast(s_ws[(size_t)b * A_ + a1] + hidden_ws[(size_t)b * A_ + a1]);
#pragma unroll
        for (int o = 32; o >= 1; o >>= 1) part += __shfl_down(part, o, 64);
        if ((t & 63) == 0) red[t >> 6] = part;
        __syncthreads();
        if (t == 0) sa_s = red[0] + red[1] + red[2] + red[3] + bas[0];
        __syncthreads();
    }

    float zv = (t < P_) ? (z_ws[(size_t)b * P_ + t] + bav[0]) : -1e30f;

    float m = zv;
#pragma unroll
    for (int o = 32; o >= 1; o >>= 1) m = fmaxf(m, __shfl_xor(m, o, 64));
    if ((t & 63) == 0) red[t >> 6] = m;
    __syncthreads();
    if (t == 0) bm_s = fmaxf(fmaxf(red[0], red[1]), fmaxf(red[2], red[3]));
    __syncthreads();
    float m1 = bm_s;

    float e = (t < P_) ? __expf(zv - m1) : 0.f;
    float s = e;
#pragma unroll
    for (int o = 32; o >= 1; o >>= 1) s += __shfl_xor(s, o, 64);
    if ((t & 63) == 0) red[t >> 6] = s;
    __syncthreads();
    if (t == 0) bl_s = red[0] + red[1] + red[2] + red[3];
    __syncthreads();
    float l1 = bl_s;

    if (t < P_) {
        float alpha = e / l1;
        alpha_ws[(size_t)b * P_ + t] = alpha;
        out[OUT_ALPHA + (size_t)b * P_ + t] = alpha;
    }
    float sa = sa_s;
    float m2 = fmaxf(m1, sa);
    float l2 = __expf(m1 - m2) * l1 + __expf(sa - m2);
    float beta = __expf(sa - m2) / l2;
    if (t == 0) {
        beta_ws[b] = beta;
        out[OUT_BETA + b] = beta;
    }
}

// ---------------- K4a: ct_ws[b][:] += E[b,pc-chunk]^T alpha ----------------
#define PCH 49
__global__ __launch_bounds__(256) void k4_ct_partial(
    const float* __restrict__ E, const float* __restrict__ alpha_ws,
    float* __restrict__ ct_ws)
{
    __shared__ float al[PCH];
    int b = blockIdx.x, pc = blockIdx.y, t = threadIdx.x;
    int pbase = pc * PCH;
    if (t < PCH) al[t] = alpha_ws[(size_t)b * P_ + pbase + t];
    __syncthreads();
    const float* eb = E + ((size_t)b * P_ + pbase) * D_ + 2 * t;
    float a0 = 0.f, a1 = 0.f;
#pragma unroll 7
    for (int p = 0; p < PCH; ++p) {
        float2 u = *(const float2*)(eb + (size_t)p * D_);
        float ap = al[p];
        a0 = fmaf(ap, u.x, a0);
        a1 = fmaf(ap, u.y, a1);
    }
    atomicAdd(&ct_ws[(size_t)b * D_ + 2 * t],     a0);
    atomicAdd(&ct_ws[(size_t)b * D_ + 2 * t + 1], a1);
}

// ---------------- K4b: c_hat = beta*st + (1-beta)*c_t ----------------
__global__ __launch_bounds__(256) void k4_combine(
    const float* __restrict__ st, const float* __restrict__ ct_ws,
    const float* __restrict__ beta_ws, float* __restrict__ out)
{
    int b = blockIdx.x, t = threadIdx.x;
    float beta = beta_ws[b];
    float2 su = *(const float2*)(st + (size_t)b * D_ + 2 * t);
    float2 cu = *(const float2*)(ct_ws + (size_t)b * D_ + 2 * t);
    float c0 = beta * su.x + (1.f - beta) * cu.x;
    float c1 = beta * su.y + (1.f - beta) * cu.y;
    *(float2*)(out + (size_t)b * D_ + 2 * t) = make_float2(c0, c1);
}

extern "C" void kernel_launch(void* const* d_in, const int* in_sizes, int n_in,
                              void* d_out, int out_size, void* d_ws, size_t ws_size,
                              hipStream_t stream)
{
    (void)in_sizes; (void)n_in; (void)out_size; (void)ws_size;
    const float* E   = (const float*)d_in[0];
    const float* dh  = (const float*)d_in[1];
    const float* st  = (const float*)d_in[2];
    const float* Wv  = (const float*)d_in[3];
    const float* bv  = (const float*)d_in[4];
    const float* Wh  = (const float*)d_in[5];
    const float* bh  = (const float*)d_in[6];
    const float* Ws  = (const float*)d_in[7];
    const float* bs  = (const float*)d_in[8];
    const float* Wav = (const float*)d_in[9];
    const float* bav = (const float*)d_in[10];
    const float* Was = (const float*)d_in[11];
    const float* bas = (const float*)d_in[12];
    float* out = (float*)d_out;

    char* ws = (char*)d_ws;
    ushort_t* WvT      = (ushort_t*)(ws);            //  524288 B
    ushort_t* WhT      = (ushort_t*)(ws + 524288);   //  524288 B
    ushort_t* WsT      = (ushort_t*)(ws + 1048576);  //  524288 B
    float*    hidden_w = (float*)(ws + 1572864);     //  524288 B
    float*    s_w      = (float*)(ws + 2097152);     //  524288 B
    float*    z_w      = (float*)(ws + 2621440);     //  200704 B
    float*    alpha_w  = (float*)(ws + 2822144);     //  200704 B
    float*    beta_w   = (float*)(ws + 3022848);     //    1024 B
    float*    ct_w     = (float*)(ws + 3023872);     //  524288 B
    ushort_t* dhbf     = (ushort_t*)(ws + 3548160);  //  262144 B
    ushort_t* stbf     = (ushort_t*)(ws + 3810304);  //  262144 B
    ushort_t* Ebf      = (ushort_t*)(ws + 4072448);  // 51380224 B (~52.9 MB total)

    k0_transpose<<<dim3(16, 16), 256, 0, stream>>>(Wv, WvT);
    k0_transpose<<<dim3(16, 16), 256, 0, stream>>>(Wh, WhT);
    k0_transpose<<<dim3(16, 16), 256, 0, stream>>>(Ws, WsT);
    kcvt_small<<<128, 256, 0, stream>>>(dh, st, dhbf, stbf, z_w, ct_w);
    kE_cvt<<<(B_ * P_ * D_) / 4 / 512, 256, 0, stream>>>(E, Ebf);
    k1_mfma<<<dim3(4, 2, 2), 256, 0, stream>>>(dhbf, stbf, WhT, WsT, bh, bs,
                                               hidden_w, s_w);
    k2_z_bf<<<dim3((B_ * P_) / BM, A_ / BN), 256, 0, stream>>>(
        Ebf, WvT, hidden_w, bv, Wav, z_w);
    k3_softmax<<<256, 256, 0, stream>>>(z_w, hidden_w, s_w, Was, bas, bav,
                                        alpha_w, beta_w, out);
    k4_ct_partial<<<dim3(B_, P_ / PCH), 256, 0, stream>>>(E, alpha_w, ct_w);
    k4_combine<<<256, 256, 0, stream>>>(st, ct_w, beta_w, out);
}

// Round 8
// 261.930 us; speedup vs baseline: 1.3170x; 1.0464x over previous
//
#include <hip/hip_runtime.h>
#include <hip/hip_bf16.h>
#include <cstdint>

#define B_ 256
#define P_ 196
#define D_ 512
#define A_ 512

#define OUT_CHAT  0
#define OUT_ALPHA (B_*D_)            // 131072
#define OUT_BETA  (B_*D_ + B_*P_)    // 181248

typedef unsigned short ushort_t;
typedef uint32_t u32;
typedef uint64_t u64;
typedef __attribute__((ext_vector_type(8))) __bf16 bf16x8;
typedef __attribute__((ext_vector_type(4))) float f32x4;

__device__ __forceinline__ ushort_t f2bf(float f) {
    union { float f; u32 i; } v; v.f = f;
    u32 r = (v.i + 0x7fffu + ((v.i >> 16) & 1u)) >> 16;
    return (ushort_t)r;
}
__device__ __forceinline__ float bfbits2f(u32 lo16) {
    union { u32 i; float f; } v; v.i = lo16 << 16; return v.f;
}
// HW packed f32->bf16 (v_cvt_pk_bf16_f32 on gfx950)
__device__ __forceinline__ u32 cvt2bf(float x, float y) {
    union { __hip_bfloat162 h; u32 u; } v;
    v.h = __float22bfloat162_rn(make_float2(x, y));
    return v.u;
}
__device__ __forceinline__ float tanh_fast(float x) {
    float e = __expf(2.0f * x);
    return 1.0f - 2.0f / (e + 1.0f);
}
// async 16B global->LDS (global_load_lds_dwordx4); LDS dest must be
// wave-uniform base + lane*16 — our staging maps guarantee that.
__device__ __forceinline__ void async_load16(const ushort_t* g, ushort_t* l) {
    __builtin_amdgcn_global_load_lds(
        (const __attribute__((address_space(1))) unsigned int*)g,
        (__attribute__((address_space(3))) unsigned int*)l, 16, 0, 0);
}

// ------- K0: WT[a][d] = bf16(W[d][a]) for W in {Wv, Wh, Ws} (z-indexed) -------
__global__ __launch_bounds__(256) void k0_all(
    const float* __restrict__ Wv, const float* __restrict__ Wh,
    const float* __restrict__ Ws,
    ushort_t* __restrict__ WvT, ushort_t* __restrict__ WhT,
    ushort_t* __restrict__ WsT)
{
    __shared__ ushort_t tile[32][33];
    const float* W = (blockIdx.z == 0) ? Wv : (blockIdx.z == 1) ? Wh : Ws;
    ushort_t*    WT = (blockIdx.z == 0) ? WvT : (blockIdx.z == 1) ? WhT : WsT;
    int bx = blockIdx.x, by = blockIdx.y;
    int t = threadIdx.x, r = t >> 5, c = t & 31;
#pragma unroll
    for (int i = 0; i < 4; ++i) {
        int row = r + 8 * i;
        tile[row][c] = f2bf(W[(size_t)(by * 32 + row) * A_ + bx * 32 + c]);
    }
    __syncthreads();
#pragma unroll
    for (int i = 0; i < 4; ++i) {
        int row = r + 8 * i;
        WT[(size_t)(bx * 32 + row) * D_ + by * 32 + c] = tile[c][row];
    }
}

// ---- kE_plus: Ebf = bf16(E) (blocks < 12544); dh/st -> bf16 (last 128) ----
__global__ __launch_bounds__(256) void kE_plus(
    const float* __restrict__ E, const float* __restrict__ dh,
    const float* __restrict__ st,
    ushort_t* __restrict__ Ebf, ushort_t* __restrict__ dhbf,
    ushort_t* __restrict__ stbf)
{
    int bx = blockIdx.x;
    if (bx < 12544) {
        size_t i0 = (size_t)bx * 512 + threadIdx.x;
        const float4* src = (const float4*)E;
        u64* dst = (u64*)Ebf;
        float4 v0 = src[i0];
        float4 v1 = src[i0 + 256];
        dst[i0]       = (u64)cvt2bf(v0.x, v0.y) | ((u64)cvt2bf(v0.z, v0.w) << 32);
        dst[i0 + 256] = (u64)cvt2bf(v1.x, v1.y) | ((u64)cvt2bf(v1.z, v1.w) << 32);
    } else {
        int gid = (bx - 12544) * 256 + threadIdx.x;   // 0..32767
        float4 dv = ((const float4*)dh)[gid];
        float4 sv = ((const float4*)st)[gid];
        ((u64*)dhbf)[gid] = (u64)cvt2bf(dv.x, dv.y) | ((u64)cvt2bf(dv.z, dv.w) << 32);
        ((u64*)stbf)[gid] = (u64)cvt2bf(sv.x, sv.y) | ((u64)cvt2bf(sv.z, sv.w) << 32);
    }
}

#define PADK 72   // used by k1 only

// ---- k1_mfma: hidden = dh@Wh+bh (z=0) and s = st@Ws+bs (z=1) ----
__global__ __launch_bounds__(256) void k1_mfma(
    const ushort_t* __restrict__ dhbf, const ushort_t* __restrict__ stbf,
    const ushort_t* __restrict__ WhT,  const ushort_t* __restrict__ WsT,
    const float* __restrict__ bh, const float* __restrict__ bs,
    float* __restrict__ hidden_ws, float* __restrict__ s_ws)
{
    __shared__ ushort_t As[128 * PADK];
    __shared__ ushort_t Bs[128 * PADK];

    int mat = blockIdx.z;
    const ushort_t* Abf = mat ? stbf : dhbf;
    const ushort_t* WT  = mat ? WsT  : WhT;
    const float*    bia = mat ? bs   : bh;
    float*          outp = mat ? s_ws : hidden_ws;

    int tid = threadIdx.x;
    int m0 = blockIdx.y * 128;
    int n0 = blockIdx.x * 128;

    int lane = tid & 63, w = tid >> 6;
    int wm = w & 1, wn = w >> 1;
    int col = lane & 15, q = lane >> 4;

    f32x4 acc[4][4];
#pragma unroll
    for (int tm = 0; tm < 4; ++tm)
#pragma unroll
        for (int tn = 0; tn < 4; ++tn)
            acc[tm][tn] = (f32x4){0.f, 0.f, 0.f, 0.f};

    const ushort_t* arow = As + (wm * 64 + col) * PADK + q * 8;
    const ushort_t* brow = Bs + (wn * 64 + col) * PADK + q * 8;

    int sr = tid >> 3, sc = tid & 7;
    for (int kt = 0; kt < D_ / 64; ++kt) {
#pragma unroll
        for (int i = 0; i < 4; ++i) {
            int row = sr + i * 32;
            *(uint4*)(As + row * PADK + sc * 8) =
                *(const uint4*)(Abf + (size_t)(m0 + row) * D_ + kt * 64 + sc * 8);
            *(uint4*)(Bs + row * PADK + sc * 8) =
                *(const uint4*)(WT + (size_t)(n0 + row) * D_ + kt * 64 + sc * 8);
        }
        __syncthreads();
#pragma unroll
        for (int ks = 0; ks < 2; ++ks) {
            bf16x8 afr[4];
#pragma unroll
            for (int tm = 0; tm < 4; ++tm)
                afr[tm] = *(const bf16x8*)(arow + tm * 16 * PADK + ks * 32);
#pragma unroll
            for (int tn = 0; tn < 4; ++tn) {
                bf16x8 bfr = *(const bf16x8*)(brow + tn * 16 * PADK + ks * 32);
#pragma unroll
                for (int tm = 0; tm < 4; ++tm)
                    acc[tm][tn] = __builtin_amdgcn_mfma_f32_16x16x32_bf16(
                        afr[tm], bfr, acc[tm][tn], 0, 0, 0);
            }
        }
        __syncthreads();
    }

#pragma unroll
    for (int tm = 0; tm < 4; ++tm)
#pragma unroll
        for (int r = 0; r < 4; ++r) {
            int b = m0 + wm * 64 + tm * 16 + q * 4 + r;
#pragma unroll
            for (int tn = 0; tn < 4; ++tn) {
                int n = n0 + wn * 64 + tn * 16 + col;
                outp[(size_t)b * A_ + n] = acc[tm][tn][r] + bia[n];
            }
        }
}

// ---- K2: z partials via async-LDS GEMM. BM=128, BN=256, BK=64. ----
// Unpadded tiles (64-elem pitch) + chunk-XOR swizzle (chunk ^ (row&7)) applied
// on the GLOBAL side so global_load_lds's contiguous lane->LDS map works and
// ds_read_b128 frag reads alias at most 2-way (free).
#define BM 128
#define BN 256
#define BKk 64
__global__ __launch_bounds__(256, 3) void k2_z_bf(
    const ushort_t* __restrict__ Ebf, const ushort_t* __restrict__ WvT,
    const float* __restrict__ hidden_ws, const float* __restrict__ bv,
    const float* __restrict__ Wav, float* __restrict__ z2_ws)
{
    __shared__ ushort_t As[BM * BKk];   // 16 KB
    __shared__ ushort_t Bs[BN * BKk];   // 32 KB
    __shared__ float hv_s[2][BN];
    __shared__ float wav_s[BN];
    __shared__ float zpart[2][BM];

    int tid = threadIdx.x;
    int m0  = blockIdx.x * BM;
    int n0  = blockIdx.y * BN;
    int b0  = m0 / P_;
    int b1  = (m0 + BM - 1) / P_;

    {
        int a = n0 + tid;
        float bva = bv[a];
        hv_s[0][tid] = hidden_ws[(size_t)b0 * A_ + a] + bva;
        hv_s[1][tid] = hidden_ws[(size_t)b1 * A_ + a] + bva;
        wav_s[tid]   = Wav[a];
    }

    int lane = tid & 63, w = tid >> 6;
    int wm = w & 1, wn = w >> 1;
    int col = lane & 15, q = lane >> 4;

    f32x4 acc[4][8];
#pragma unroll
    for (int tm = 0; tm < 4; ++tm)
#pragma unroll
        for (int tn = 0; tn < 8; ++tn)
            acc[tm][tn] = (f32x4){0.f, 0.f, 0.f, 0.f};

    // staging bases: thread handles (row = tid>>3 + 32*i, chunk pos = tid&7),
    // fetching global chunk (pos ^ (row&7)); row&7 invariant under +32.
    int srow = tid >> 3, spos = tid & 7;
    int gch  = spos ^ (srow & 7);
    const ushort_t* agb = Ebf + (size_t)(m0 + srow) * D_ + gch * 8;
    const ushort_t* bgb = WvT + (size_t)(n0 + srow) * D_ + gch * 8;
    ushort_t* alb = As + tid * 8;
    ushort_t* blb = Bs + tid * 8;

    // frag read XOR: row&7 == col&7 for all frag rows
    int fx = col & 7;

    for (int kt = 0; kt < D_ / BKk; ++kt) {
#pragma unroll
        for (int i = 0; i < 4; ++i)
            async_load16(agb + (size_t)i * 32 * D_ + kt * BKk, alb + i * 2048);
#pragma unroll
        for (int i = 0; i < 8; ++i)
            async_load16(bgb + (size_t)i * 32 * D_ + kt * BKk, blb + i * 2048);
        __syncthreads();   // drains vmcnt(0) -> async loads landed
#pragma unroll
        for (int ks = 0; ks < 2; ++ks) {
            bf16x8 afr[4];
#pragma unroll
            for (int tm = 0; tm < 4; ++tm)
                afr[tm] = *(const bf16x8*)(As + (wm * 64 + tm * 16 + col) * BKk
                                              + (((ks * 4 + q) ^ fx) * 8));
#pragma unroll
            for (int tn = 0; tn < 8; ++tn) {
                bf16x8 bfr = *(const bf16x8*)(Bs + (wn * 128 + tn * 16 + col) * BKk
                                                 + (((ks * 4 + q) ^ fx) * 8));
#pragma unroll
                for (int tm = 0; tm < 4; ++tm)
                    acc[tm][tn] = __builtin_amdgcn_mfma_f32_16x16x32_bf16(
                        afr[tm], bfr, acc[tm][tn], 0, 0, 0);
            }
        }
        __syncthreads();
    }

#pragma unroll
    for (int tm = 0; tm < 4; ++tm) {
#pragma unroll
        for (int r = 0; r < 4; ++r) {
            int row = wm * 64 + tm * 16 + q * 4 + r;
            int m   = m0 + row;
            int bsel = (m / P_) - b0;
            float zr = 0.f;
#pragma unroll
            for (int tn = 0; tn < 8; ++tn) {
                int nl = wn * 128 + tn * 16 + col;
                zr += wav_s[nl] * tanh_fast(acc[tm][tn][r] + hv_s[bsel][nl]);
            }
#pragma unroll
            for (int msk = 1; msk < 16; msk <<= 1)
                zr += __shfl_xor(zr, msk, 64);
            if (col == 0) zpart[wn][row] = zr;
        }
    }
    __syncthreads();
    if (tid < BM)   // partial per n-chunk; k3 sums the two chunks (no atomics)
        z2_ws[(size_t)blockIdx.y * (B_ * P_) + m0 + tid] =
            zpart[0][tid] + zpart[1][tid];
}

// ---- K3: s_att; softmax(z+bav) -> alpha; extended -> beta ----
__global__ __launch_bounds__(256) void k3_softmax(
    const float* __restrict__ z2_ws, const float* __restrict__ hidden_ws,
    const float* __restrict__ s_ws, const float* __restrict__ Was,
    const float* __restrict__ bas, const float* __restrict__ bav,
    float* __restrict__ alpha_ws, float* __restrict__ beta_ws,
    float* __restrict__ out)
{
    __shared__ float red[4];
    __shared__ float bm_s, bl_s, sa_s;
    int b = blockIdx.x, t = threadIdx.x;

    {
        int a0 = t, a1 = t + 256;
        float part = Was[a0] * tanh_fast(s_ws[(size_t)b * A_ + a0] + hidden_ws[(size_t)b * A_ + a0])
                   + Was[a1] * tanh_fast(s_ws[(size_t)b * A_ + a1] + hidden_ws[(size_t)b * A_ + a1]);
#pragma unroll
        for (int o = 32; o >= 1; o >>= 1) part += __shfl_down(part, o, 64);
        if ((t & 63) == 0) red[t >> 6] = part;
        __syncthreads();
        if (t == 0) sa_s = red[0] + red[1] + red[2] + red[3] + bas[0];
        __syncthreads();
    }

    float zv = (t < P_) ? (z2_ws[(size_t)b * P_ + t]
                         + z2_ws[(size_t)(B_ * P_) + (size_t)b * P_ + t] + bav[0])
                        : -1e30f;

    float m = zv;
#pragma unroll
    for (int o = 32; o >= 1; o >>= 1) m = fmaxf(m, __shfl_xor(m, o, 64));
    if ((t & 63) == 0) red[t >> 6] = m;
    __syncthreads();
    if (t == 0) bm_s = fmaxf(fmaxf(red[0], red[1]), fmaxf(red[2], red[3]));
    __syncthreads();
    float m1 = bm_s;

    float e = (t < P_) ? __expf(zv - m1) : 0.f;
    float s = e;
#pragma unroll
    for (int o = 32; o >= 1; o >>= 1) s += __shfl_xor(s, o, 64);
    if ((t & 63) == 0) red[t >> 6] = s;
    __syncthreads();
    if (t == 0) bl_s = red[0] + red[1] + red[2] + red[3];
    __syncthreads();
    float l1 = bl_s;

    if (t < P_) {
        float alpha = e / l1;
        alpha_ws[(size_t)b * P_ + t] = alpha;
        out[OUT_ALPHA + (size_t)b * P_ + t] = alpha;
    }
    float sa = sa_s;
    float m2 = fmaxf(m1, sa);
    float l2 = __expf(m1 - m2) * l1 + __expf(sa - m2);
    float beta = __expf(sa - m2) / l2;
    if (t == 0) {
        beta_ws[b] = beta;
        out[OUT_BETA + b] = beta;
    }
}

// ---- K4a: ctp[pc][b][:] = E[b, pc-chunk]^T alpha  (f32 E, no atomics) ----
#define PCH 98
__global__ __launch_bounds__(256) void k4_ct_partial(
    const float* __restrict__ E, const float* __restrict__ alpha_ws,
    float* __restrict__ ctp)
{
    __shared__ float al[PCH];
    int b = blockIdx.x, pc = blockIdx.y, t = threadIdx.x;
    int pbase = pc * PCH;
    if (t < PCH) al[t] = alpha_ws[(size_t)b * P_ + pbase + t];
    __syncthreads();
    const float* eb = E + ((size_t)b * P_ + pbase) * D_ + 2 * t;
    float a0 = 0.f, a1 = 0.f;
#pragma unroll 7
    for (int p = 0; p < PCH; ++p) {
        float2 u = *(const float2*)(eb + (size_t)p * D_);
        float ap = al[p];
        a0 = fmaf(ap, u.x, a0);
        a1 = fmaf(ap, u.y, a1);
    }
    *(float2*)(ctp + ((size_t)pc * B_ + b) * D_ + 2 * t) = make_float2(a0, a1);
}

// ---- K4b: c_hat = beta*st + (1-beta)*(ctp0+ctp1) ----
__global__ __launch_bounds__(256) void k4_combine(
    const float* __restrict__ st, const float* __restrict__ ctp,
    const float* __restrict__ beta_ws, float* __restrict__ out)
{
    int b = blockIdx.x, t = threadIdx.x;
    float beta = beta_ws[b];
    float2 su = *(const float2*)(st + (size_t)b * D_ + 2 * t);
    float2 c0v = *(const float2*)(ctp + (size_t)b * D_ + 2 * t);
    float2 c1v = *(const float2*)(ctp + ((size_t)B_ + b) * D_ + 2 * t);
    float c0 = beta * su.x + (1.f - beta) * (c0v.x + c1v.x);
    float c1 = beta * su.y + (1.f - beta) * (c0v.y + c1v.y);
    *(float2*)(out + (size_t)b * D_ + 2 * t) = make_float2(c0, c1);
}

extern "C" void kernel_launch(void* const* d_in, const int* in_sizes, int n_in,
                              void* d_out, int out_size, void* d_ws, size_t ws_size,
                              hipStream_t stream)
{
    (void)in_sizes; (void)n_in; (void)out_size; (void)ws_size;
    const float* E   = (const float*)d_in[0];
    const float* dh  = (const float*)d_in[1];
    const float* st  = (const float*)d_in[2];
    const float* Wv  = (const float*)d_in[3];
    const float* bv  = (const float*)d_in[4];
    const float* Wh  = (const float*)d_in[5];
    const float* bh  = (const float*)d_in[6];
    const float* Ws  = (const float*)d_in[7];
    const float* bs  = (const float*)d_in[8];
    const float* Wav = (const float*)d_in[9];
    const float* bav = (const float*)d_in[10];
    const float* Was = (const float*)d_in[11];
    const float* bas = (const float*)d_in[12];
    float* out = (float*)d_out;

    char* ws = (char*)d_ws;
    ushort_t* WvT     = (ushort_t*)(ws);            //  524288
    ushort_t* WhT     = (ushort_t*)(ws + 524288);   //  524288
    ushort_t* WsT     = (ushort_t*)(ws + 1048576);  //  524288
    float*    alpha_w = (float*)(ws + 1572864);     //  200704
    float*    beta_w  = (float*)(ws + 1773568);     //    1024
    float*    z2_w    = (float*)(ws + 1774592);     //  401408 (2 x B x P)
    ushort_t* dhbf    = (ushort_t*)(ws + 2176000);  //  262144
    ushort_t* stbf    = (ushort_t*)(ws + 2438144);  //  262144
    float*    hidden_w= (float*)(ws + 2700288);     //  524288
    float*    s_w     = (float*)(ws + 3224576);     //  524288
    // ctp overlays hidden_w + s_w (both dead after k3; k4a runs after k3)
    float*    ctp_w   = (float*)(ws + 2700288);     // 1048576 (2 x B x D)
    ushort_t* Ebf     = (ushort_t*)(ws + 3748864);  // 51380224 (total ~55.1 MB)

    k0_all<<<dim3(16, 16, 3), 256, 0, stream>>>(Wv, Wh, Ws, WvT, WhT, WsT);
    kE_plus<<<12544 + 128, 256, 0, stream>>>(E, dh, st, Ebf, dhbf, stbf);
    k1_mfma<<<dim3(4, 2, 2), 256, 0, stream>>>(dhbf, stbf, WhT, WsT, bh, bs,
                                               hidden_w, s_w);
    k2_z_bf<<<dim3((B_ * P_) / BM, A_ / BN), 256, 0, stream>>>(
        Ebf, WvT, hidden_w, bv, Wav, z2_w);
    k3_softmax<<<256, 256, 0, stream>>>(z2_w, hidden_w, s_w, Was, bas, bav,
                                        alpha_w, beta_w, out);
    k4_ct_partial<<<dim3(B_, 2), 256, 0, stream>>>(E, alpha_w, ctp_w);
    k4_combine<<<256, 256, 0, stream>>>(st, ctp_w, beta_w, out);
}

// Round 9
// 258.050 us; speedup vs baseline: 1.3368x; 1.0150x over previous
//
#include <hip/hip_runtime.h>
#include <hip/hip_bf16.h>
#include <cstdint>

#define B_ 256
#define P_ 196
#define D_ 512
#define A_ 512

#define OUT_CHAT  0
#define OUT_ALPHA (B_*D_)            // 131072
#define OUT_BETA  (B_*D_ + B_*P_)    // 181248

typedef unsigned short ushort_t;
typedef uint32_t u32;
typedef uint64_t u64;
typedef __attribute__((ext_vector_type(8))) __bf16 bf16x8;
typedef __attribute__((ext_vector_type(4))) float f32x4;

__device__ __forceinline__ ushort_t f2bf(float f) {
    union { float f; u32 i; } v; v.f = f;
    u32 r = (v.i + 0x7fffu + ((v.i >> 16) & 1u)) >> 16;
    return (ushort_t)r;
}
__device__ __forceinline__ float bfbits2f(u32 lo16) {
    union { u32 i; float f; } v; v.i = lo16 << 16; return v.f;
}
// HW packed f32->bf16 (v_cvt_pk_bf16_f32 on gfx950)
__device__ __forceinline__ u32 cvt2bf(float x, float y) {
    union { __hip_bfloat162 h; u32 u; } v;
    v.h = __float22bfloat162_rn(make_float2(x, y));
    return v.u;
}
__device__ __forceinline__ float tanh_fast(float x) {
    float e = __expf(2.0f * x);
    return 1.0f - 2.0f / (e + 1.0f);
}
// async 16B global->LDS (global_load_lds_dwordx4); LDS dest must be
// wave-uniform base + lane*16 — our staging maps guarantee that.
__device__ __forceinline__ void async_load16(const ushort_t* g, ushort_t* l) {
    __builtin_amdgcn_global_load_lds(
        (const __attribute__((address_space(1))) unsigned int*)g,
        (__attribute__((address_space(3))) unsigned int*)l, 16, 0, 0);
}

// ---- k_prep: [0,12544) Ebf=bf16(E); [12544,12672) dh/st cvt;
//              [12672,13440) transposes WT[a][d]=bf16(W[d][a]) ----
__global__ __launch_bounds__(256) void k_prep(
    const float* __restrict__ E, const float* __restrict__ dh,
    const float* __restrict__ st,
    const float* __restrict__ Wv, const float* __restrict__ Wh,
    const float* __restrict__ Ws,
    ushort_t* __restrict__ Ebf, ushort_t* __restrict__ dhbf,
    ushort_t* __restrict__ stbf,
    ushort_t* __restrict__ WvT, ushort_t* __restrict__ WhT,
    ushort_t* __restrict__ WsT)
{
    __shared__ ushort_t tile[32][33];
    int bx = blockIdx.x;
    if (bx < 12544) {
        size_t i0 = (size_t)bx * 512 + threadIdx.x;
        const float4* src = (const float4*)E;
        u64* dst = (u64*)Ebf;
        float4 v0 = src[i0];
        float4 v1 = src[i0 + 256];
        dst[i0]       = (u64)cvt2bf(v0.x, v0.y) | ((u64)cvt2bf(v0.z, v0.w) << 32);
        dst[i0 + 256] = (u64)cvt2bf(v1.x, v1.y) | ((u64)cvt2bf(v1.z, v1.w) << 32);
    } else if (bx < 12672) {
        int gid = (bx - 12544) * 256 + threadIdx.x;   // 0..32767
        float4 dv = ((const float4*)dh)[gid];
        float4 sv = ((const float4*)st)[gid];
        ((u64*)dhbf)[gid] = (u64)cvt2bf(dv.x, dv.y) | ((u64)cvt2bf(dv.z, dv.w) << 32);
        ((u64*)stbf)[gid] = (u64)cvt2bf(sv.x, sv.y) | ((u64)cvt2bf(sv.z, sv.w) << 32);
    } else {
        int idx = bx - 12672;            // 0..767
        int z   = idx >> 8;              // which matrix
        int rem = idx & 255;
        int tby = rem >> 4, tbx = rem & 15;
        const float* W  = (z == 0) ? Wv  : (z == 1) ? Wh  : Ws;
        ushort_t*    WT = (z == 0) ? WvT : (z == 1) ? WhT : WsT;
        int t = threadIdx.x, r = t >> 5, c = t & 31;
#pragma unroll
        for (int i = 0; i < 4; ++i) {
            int row = r + 8 * i;
            tile[row][c] = f2bf(W[(size_t)(tby * 32 + row) * A_ + tbx * 32 + c]);
        }
        __syncthreads();
#pragma unroll
        for (int i = 0; i < 4; ++i) {
            int row = r + 8 * i;
            WT[(size_t)(tbx * 32 + row) * D_ + tby * 32 + c] = tile[c][row];
        }
    }
}

#define PADK 72   // used by k1 only

// ---- k1_mfma: hidden = dh@Wh+bh (z=0) and s = st@Ws+bs (z=1) ----
__global__ __launch_bounds__(256) void k1_mfma(
    const ushort_t* __restrict__ dhbf, const ushort_t* __restrict__ stbf,
    const ushort_t* __restrict__ WhT,  const ushort_t* __restrict__ WsT,
    const float* __restrict__ bh, const float* __restrict__ bs,
    float* __restrict__ hidden_ws, float* __restrict__ s_ws)
{
    __shared__ ushort_t As[128 * PADK];
    __shared__ ushort_t Bs[128 * PADK];

    int mat = blockIdx.z;
    const ushort_t* Abf = mat ? stbf : dhbf;
    const ushort_t* WT  = mat ? WsT  : WhT;
    const float*    bia = mat ? bs   : bh;
    float*          outp = mat ? s_ws : hidden_ws;

    int tid = threadIdx.x;
    int m0 = blockIdx.y * 128;
    int n0 = blockIdx.x * 128;

    int lane = tid & 63, w = tid >> 6;
    int wm = w & 1, wn = w >> 1;
    int col = lane & 15, q = lane >> 4;

    f32x4 acc[4][4];
#pragma unroll
    for (int tm = 0; tm < 4; ++tm)
#pragma unroll
        for (int tn = 0; tn < 4; ++tn)
            acc[tm][tn] = (f32x4){0.f, 0.f, 0.f, 0.f};

    const ushort_t* arow = As + (wm * 64 + col) * PADK + q * 8;
    const ushort_t* brow = Bs + (wn * 64 + col) * PADK + q * 8;

    int sr = tid >> 3, sc = tid & 7;
    for (int kt = 0; kt < D_ / 64; ++kt) {
#pragma unroll
        for (int i = 0; i < 4; ++i) {
            int row = sr + i * 32;
            *(uint4*)(As + row * PADK + sc * 8) =
                *(const uint4*)(Abf + (size_t)(m0 + row) * D_ + kt * 64 + sc * 8);
            *(uint4*)(Bs + row * PADK + sc * 8) =
                *(const uint4*)(WT + (size_t)(n0 + row) * D_ + kt * 64 + sc * 8);
        }
        __syncthreads();
#pragma unroll
        for (int ks = 0; ks < 2; ++ks) {
            bf16x8 afr[4];
#pragma unroll
            for (int tm = 0; tm < 4; ++tm)
                afr[tm] = *(const bf16x8*)(arow + tm * 16 * PADK + ks * 32);
#pragma unroll
            for (int tn = 0; tn < 4; ++tn) {
                bf16x8 bfr = *(const bf16x8*)(brow + tn * 16 * PADK + ks * 32);
#pragma unroll
                for (int tm = 0; tm < 4; ++tm)
                    acc[tm][tn] = __builtin_amdgcn_mfma_f32_16x16x32_bf16(
                        afr[tm], bfr, acc[tm][tn], 0, 0, 0);
            }
        }
        __syncthreads();
    }

#pragma unroll
    for (int tm = 0; tm < 4; ++tm)
#pragma unroll
        for (int r = 0; r < 4; ++r) {
            int b = m0 + wm * 64 + tm * 16 + q * 4 + r;
#pragma unroll
            for (int tn = 0; tn < 4; ++tn) {
                int n = n0 + wn * 64 + tn * 16 + col;
                outp[(size_t)b * A_ + n] = acc[tm][tn][r] + bia[n];
            }
        }
}

// ---- K2: z partials via async-LDS GEMM. BM=128, BN=256, BK=64. ----
#define BM 128
#define BN 256
#define BKk 64
__global__ __launch_bounds__(256, 3) void k2_z_bf(
    const ushort_t* __restrict__ Ebf, const ushort_t* __restrict__ WvT,
    const float* __restrict__ hidden_ws, const float* __restrict__ bv,
    const float* __restrict__ Wav, float* __restrict__ z2_ws)
{
    __shared__ ushort_t As[BM * BKk];   // 16 KB
    __shared__ ushort_t Bs[BN * BKk];   // 32 KB
    __shared__ float hv_s[2][BN];
    __shared__ float wav_s[BN];
    __shared__ float zpart[2][BM];

    int tid = threadIdx.x;
    int m0  = blockIdx.x * BM;
    int n0  = blockIdx.y * BN;
    int b0  = m0 / P_;
    int b1  = (m0 + BM - 1) / P_;

    {
        int a = n0 + tid;
        float bva = bv[a];
        hv_s[0][tid] = hidden_ws[(size_t)b0 * A_ + a] + bva;
        hv_s[1][tid] = hidden_ws[(size_t)b1 * A_ + a] + bva;
        wav_s[tid]   = Wav[a];
    }

    int lane = tid & 63, w = tid >> 6;
    int wm = w & 1, wn = w >> 1;
    int col = lane & 15, q = lane >> 4;

    f32x4 acc[4][8];
#pragma unroll
    for (int tm = 0; tm < 4; ++tm)
#pragma unroll
        for (int tn = 0; tn < 8; ++tn)
            acc[tm][tn] = (f32x4){0.f, 0.f, 0.f, 0.f};

    int srow = tid >> 3, spos = tid & 7;
    int gch  = spos ^ (srow & 7);
    const ushort_t* agb = Ebf + (size_t)(m0 + srow) * D_ + gch * 8;
    const ushort_t* bgb = WvT + (size_t)(n0 + srow) * D_ + gch * 8;
    ushort_t* alb = As + tid * 8;
    ushort_t* blb = Bs + tid * 8;

    int fx = col & 7;

    for (int kt = 0; kt < D_ / BKk; ++kt) {
#pragma unroll
        for (int i = 0; i < 4; ++i)
            async_load16(agb + (size_t)i * 32 * D_ + kt * BKk, alb + i * 2048);
#pragma unroll
        for (int i = 0; i < 8; ++i)
            async_load16(bgb + (size_t)i * 32 * D_ + kt * BKk, blb + i * 2048);
        __syncthreads();
#pragma unroll
        for (int ks = 0; ks < 2; ++ks) {
            bf16x8 afr[4];
#pragma unroll
            for (int tm = 0; tm < 4; ++tm)
                afr[tm] = *(const bf16x8*)(As + (wm * 64 + tm * 16 + col) * BKk
                                              + (((ks * 4 + q) ^ fx) * 8));
#pragma unroll
            for (int tn = 0; tn < 8; ++tn) {
                bf16x8 bfr = *(const bf16x8*)(Bs + (wn * 128 + tn * 16 + col) * BKk
                                                 + (((ks * 4 + q) ^ fx) * 8));
#pragma unroll
                for (int tm = 0; tm < 4; ++tm)
                    acc[tm][tn] = __builtin_amdgcn_mfma_f32_16x16x32_bf16(
                        afr[tm], bfr, acc[tm][tn], 0, 0, 0);
            }
        }
        __syncthreads();
    }

#pragma unroll
    for (int tm = 0; tm < 4; ++tm) {
#pragma unroll
        for (int r = 0; r < 4; ++r) {
            int row = wm * 64 + tm * 16 + q * 4 + r;
            int m   = m0 + row;
            int bsel = (m / P_) - b0;
            float zr = 0.f;
#pragma unroll
            for (int tn = 0; tn < 8; ++tn) {
                int nl = wn * 128 + tn * 16 + col;
                zr += wav_s[nl] * tanh_fast(acc[tm][tn][r] + hv_s[bsel][nl]);
            }
#pragma unroll
            for (int msk = 1; msk < 16; msk <<= 1)
                zr += __shfl_xor(zr, msk, 64);
            if (col == 0) zpart[wn][row] = zr;
        }
    }
    __syncthreads();
    if (tid < BM)
        z2_ws[(size_t)blockIdx.y * (B_ * P_) + m0 + tid] =
            zpart[0][tid] + zpart[1][tid];
}

// ---- K3: s_att; softmax(z+bav) -> alpha; extended -> beta ----
__global__ __launch_bounds__(256) void k3_softmax(
    const float* __restrict__ z2_ws, const float* __restrict__ hidden_ws,
    const float* __restrict__ s_ws, const float* __restrict__ Was,
    const float* __restrict__ bas, const float* __restrict__ bav,
    float* __restrict__ alpha_ws, float* __restrict__ beta_ws,
    float* __restrict__ out)
{
    __shared__ float red[4];
    __shared__ float bm_s, bl_s, sa_s;
    int b = blockIdx.x, t = threadIdx.x;

    {
        int a0 = t, a1 = t + 256;
        float part = Was[a0] * tanh_fast(s_ws[(size_t)b * A_ + a0] + hidden_ws[(size_t)b * A_ + a0])
                   + Was[a1] * tanh_fast(s_ws[(size_t)b * A_ + a1] + hidden_ws[(size_t)b * A_ + a1]);
#pragma unroll
        for (int o = 32; o >= 1; o >>= 1) part += __shfl_down(part, o, 64);
        if ((t & 63) == 0) red[t >> 6] = part;
        __syncthreads();
        if (t == 0) sa_s = red[0] + red[1] + red[2] + red[3] + bas[0];
        __syncthreads();
    }

    float zv = (t < P_) ? (z2_ws[(size_t)b * P_ + t]
                         + z2_ws[(size_t)(B_ * P_) + (size_t)b * P_ + t] + bav[0])
                        : -1e30f;

    float m = zv;
#pragma unroll
    for (int o = 32; o >= 1; o >>= 1) m = fmaxf(m, __shfl_xor(m, o, 64));
    if ((t & 63) == 0) red[t >> 6] = m;
    __syncthreads();
    if (t == 0) bm_s = fmaxf(fmaxf(red[0], red[1]), fmaxf(red[2], red[3]));
    __syncthreads();
    float m1 = bm_s;

    float e = (t < P_) ? __expf(zv - m1) : 0.f;
    float s = e;
#pragma unroll
    for (int o = 32; o >= 1; o >>= 1) s += __shfl_xor(s, o, 64);
    if ((t & 63) == 0) red[t >> 6] = s;
    __syncthreads();
    if (t == 0) bl_s = red[0] + red[1] + red[2] + red[3];
    __syncthreads();
    float l1 = bl_s;

    if (t < P_) {
        float alpha = e / l1;
        alpha_ws[(size_t)b * P_ + t] = alpha;
        out[OUT_ALPHA + (size_t)b * P_ + t] = alpha;
    }
    float sa = sa_s;
    float m2 = fmaxf(m1, sa);
    float l2 = __expf(m1 - m2) * l1 + __expf(sa - m2);
    float beta = __expf(sa - m2) / l2;
    if (t == 0) {
        beta_ws[b] = beta;
        out[OUT_BETA + b] = beta;
    }
}

// ---- K4: c_hat = beta*st + (1-beta) * (Ebf[b]^T alpha)  (fused, bf16 E) ----
__global__ __launch_bounds__(256) void k4_final(
    const ushort_t* __restrict__ Ebf, const float* __restrict__ st,
    const float* __restrict__ alpha_ws, const float* __restrict__ beta_ws,
    float* __restrict__ out)
{
    __shared__ float al[P_];
    int b = blockIdx.x, t = threadIdx.x;
    if (t < P_) al[t] = alpha_ws[(size_t)b * P_ + t];
    __syncthreads();
    // thread t covers d = 2t, 2t+1; one u32 (2 bf16) per p-row
    const u32* eb = (const u32*)(Ebf + (size_t)b * P_ * D_) + t;
    float a0 = 0.f, a1 = 0.f;
#pragma unroll 4
    for (int p = 0; p < P_; ++p) {
        u32 u = eb[(size_t)p * (D_ / 2)];
        float ap = al[p];
        a0 = fmaf(ap, bfbits2f(u & 0xffffu), a0);
        a1 = fmaf(ap, bfbits2f(u >> 16), a1);
    }
    float beta = beta_ws[b];
    float2 su = *(const float2*)(st + (size_t)b * D_ + 2 * t);
    float c0 = beta * su.x + (1.f - beta) * a0;
    float c1 = beta * su.y + (1.f - beta) * a1;
    *(float2*)(out + (size_t)b * D_ + 2 * t) = make_float2(c0, c1);
}

extern "C" void kernel_launch(void* const* d_in, const int* in_sizes, int n_in,
                              void* d_out, int out_size, void* d_ws, size_t ws_size,
                              hipStream_t stream)
{
    (void)in_sizes; (void)n_in; (void)out_size; (void)ws_size;
    const float* E   = (const float*)d_in[0];
    const float* dh  = (const float*)d_in[1];
    const float* st  = (const float*)d_in[2];
    const float* Wv  = (const float*)d_in[3];
    const float* bv  = (const float*)d_in[4];
    const float* Wh  = (const float*)d_in[5];
    const float* bh  = (const float*)d_in[6];
    const float* Ws  = (const float*)d_in[7];
    const float* bs  = (const float*)d_in[8];
    const float* Wav = (const float*)d_in[9];
    const float* bav = (const float*)d_in[10];
    const float* Was = (const float*)d_in[11];
    const float* bas = (const float*)d_in[12];
    float* out = (float*)d_out;

    char* ws = (char*)d_ws;
    ushort_t* WvT     = (ushort_t*)(ws);            //  524288
    ushort_t* WhT     = (ushort_t*)(ws + 524288);   //  524288
    ushort_t* WsT     = (ushort_t*)(ws + 1048576);  //  524288
    float*    alpha_w = (float*)(ws + 1572864);     //  200704
    float*    beta_w  = (float*)(ws + 1773568);     //    1024
    float*    z2_w    = (float*)(ws + 1774592);     //  401408 (2 x B x P)
    ushort_t* dhbf    = (ushort_t*)(ws + 2176000);  //  262144
    ushort_t* stbf    = (ushort_t*)(ws + 2438144);  //  262144
    float*    hidden_w= (float*)(ws + 2700288);     //  524288
    float*    s_w     = (float*)(ws + 3224576);     //  524288
    ushort_t* Ebf     = (ushort_t*)(ws + 3748864);  // 51380224 (total ~55.1 MB)

    k_prep<<<12544 + 128 + 768, 256, 0, stream>>>(E, dh, st, Wv, Wh, Ws,
                                                  Ebf, dhbf, stbf, WvT, WhT, WsT);
    k1_mfma<<<dim3(4, 2, 2), 256, 0, stream>>>(dhbf, stbf, WhT, WsT, bh, bs,
                                               hidden_w, s_w);
    k2_z_bf<<<dim3((B_ * P_) / BM, A_ / BN), 256, 0, stream>>>(
        Ebf, WvT, hidden_w, bv, Wav, z2_w);
    k3_softmax<<<256, 256, 0, stream>>>(z2_w, hidden_w, s_w, Was, bas, bav,
                                        alpha_w, beta_w, out);
    k4_final<<<256, 256, 0, stream>>>(Ebf, st, alpha_w, beta_w, out);
}